// Round 1
// baseline (136.531 us; speedup 1.0000x reference)
//
#include <hip/hip_runtime.h>
#include <math.h>

#define NB 16
#define LL 1024
#define ND 64
#define NN 8
#define NCH 32   // scan chunks
#define CLN 32   // chunk length

// workspace float offsets
#define OFF_CONST 0          // 16
#define OFF_W     16         // [2][3][128] = 768
#define OFF_AL2   784        // [2][512] = 1024
#define OFF_SA1   1808       // [2][16][1024] = 32768
#define OFF_SA2   34576      // 32768
#define OFF_XS    67344      // [2*16][64][1024] = 2097152
#define OFF_DT    2164496    // [2*16][1024][64] = 2097152
#define OFF_BC    4261648    // [2*16][1024][16] = 524288
#define OFF_P     4785936    // [2*16][32][512] = 524288
#define OFF_Q     5310224    // 524288
#define OFF_HIN   5834512    // 524288
#define OFF_YF    6358800    // [2*16][1024][64] = 2097152

__device__ __forceinline__ float wave_rsum(float v){
  #pragma unroll
  for (int o = 1; o < 64; o <<= 1) v += __shfl_xor(v, o, 64);
  return v;
}
__device__ __forceinline__ float wave_rmax(float v){
  #pragma unroll
  for (int o = 1; o < 64; o <<= 1) v = fmaxf(v, __shfl_xor(v, o, 64));
  return v;
}

// ---------------- consts: layernorm collapse vectors W1/W2/W3, A*log2e ----------------
__global__ void k_consts(const float* pre_w, const float* pre_b, const float* ln_g,
                         const float* ln_b, const float* in_w, const float* in_b_w,
                         const float* A_log, const float* A_b_log, float* ws){
  __shared__ float gw[64], gb[64], lnbs[64];
  int t = threadIdx.x;
  if (t < 64){
    float w = pre_w[t], b = pre_b[t];
    float mw = wave_rsum(w) * (1.f/64.f);
    float mb = wave_rsum(b) * (1.f/64.f);
    float wc = w - mw, bc = b - mb;
    float Av = wave_rsum(wc*wc) * (1.f/64.f);
    float Bq = wave_rsum(wc*bc) * (1.f/64.f);
    float Cq = wave_rsum(bc*bc) * (1.f/64.f);
    gw[t] = wc * ln_g[t];
    gb[t] = bc * ln_g[t];
    lnbs[t] = ln_b[t];
    if (t == 0){ ws[OFF_CONST+0] = Av; ws[OFF_CONST+1] = Bq; ws[OFF_CONST+2] = Cq; }
  }
  __syncthreads();
  {
    int br = t >> 7, e = t & 127;
    const float* iw = br ? in_b_w : in_w;
    float s1 = 0.f, s2 = 0.f, s3 = 0.f;
    for (int d = 0; d < 64; ++d){
      float w = iw[e*64 + d];
      s1 += w * gw[d]; s2 += w * gb[d]; s3 += w * lnbs[d];
    }
    ws[OFF_W + br*384 +   0 + e] = s1;
    ws[OFF_W + br*384 + 128 + e] = s2;
    ws[OFF_W + br*384 + 256 + e] = s3;
  }
  for (int i = t; i < 1024; i += 256){
    int br = i >> 9, idx = i & 511;
    const float* al = br ? A_b_log : A_log;
    ws[OFF_AL2 + i] = -expf(al[idx]) * 1.4426950408889634f;
  }
}

// ---------------- pool: max over HxW, fused a1/a2 scalar computation ----------------
__global__ void k_pool(const float* __restrict__ img1, const float* __restrict__ img2,
                       float* __restrict__ ws){
  int wv = threadIdx.x >> 6, lane = threadIdx.x & 63;
  int row = blockIdx.x * 4 + wv;          // 0..32767
  int img = row >> 14;
  int rem = row & 16383;                  // b*1024 + l
  const float* src = (img ? img2 : img1) + (size_t)rem * 1024;
  float m = -INFINITY;
  #pragma unroll
  for (int it = 0; it < 4; ++it){
    float4 v = ((const float4*)src)[it*64 + lane];
    m = fmaxf(m, fmaxf(fmaxf(v.x, v.y), fmaxf(v.z, v.w)));
  }
  m = wave_rmax(m);
  if (lane == 0){
    float Av = ws[OFF_CONST], Bq = ws[OFF_CONST+1], Cq = ws[OFF_CONST+2];
    float var = m*m*Av + 2.f*m*Bq + Cq;
    float inv = rsqrtf(var + 1e-5f);
    int b = rem >> 10, l = rem & 1023;
    int pos = img ? ((16 + b)*1024 + (1023 - l)) : rem;   // branch1 pre-reversed
    ws[OFF_SA1 + pos] = m * inv;
    ws[OFF_SA2 + pos] = inv;
  }
}

// ---------------- conv+silu (x), xproj, dt ----------------
__global__ void k_proj(const float* conv_w, const float* conv_b,
                       const float* convb_w, const float* convb_b,
                       const float* xproj_w, const float* xprojb_w,
                       const float* dt_w, const float* dt_b,
                       const float* dtb_w, const float* dtb_b,
                       float* __restrict__ ws){
  int bi = blockIdx.x;            // 2*16*8
  int chunk = bi & 7, bq = bi >> 3;
  int br = bq >> 4;
  int l0 = chunk * 128;
  int t = threadIdx.x;
  __shared__ float a1t[132], a2t[132], a3t[132];
  __shared__ float sxt[64*129];
  __shared__ float xdbt[128*20];
  const float* cw  = br ? convb_w : conv_w;
  const float* cb  = br ? convb_b : conv_b;
  const float* xpw = br ? xprojb_w : xproj_w;
  const float* dw  = br ? dtb_w : dt_w;
  const float* dbv = br ? dtb_b : dt_b;
  for (int i = t; i < 131; i += 256){
    int gl = l0 - 3 + i;
    bool ok = gl >= 0;
    a1t[i] = ok ? ws[OFF_SA1 + bq*1024 + gl] : 0.f;
    a2t[i] = ok ? ws[OFF_SA2 + bq*1024 + gl] : 0.f;
    a3t[i] = ok ? 1.f : 0.f;
  }
  __syncthreads();
  int d = t & 63, lq = t >> 6;
  {
    float cw0 = cw[d*4+0], cw1 = cw[d*4+1], cw2 = cw[d*4+2], cw3 = cw[d*4+3];
    float cbd = cb[d];
    float W1d = ws[OFF_W + br*384 + d];
    float W2d = ws[OFF_W + br*384 + 128 + d];
    float W3d = ws[OFF_W + br*384 + 256 + d];
    for (int j = 0; j < 32; ++j){
      int ll = lq*32 + j;
      float A1 = cw0*a1t[ll] + cw1*a1t[ll+1] + cw2*a1t[ll+2] + cw3*a1t[ll+3];
      float A2 = cw0*a2t[ll] + cw1*a2t[ll+1] + cw2*a2t[ll+2] + cw3*a2t[ll+3];
      float A3 = cw0*a3t[ll] + cw1*a3t[ll+1] + cw2*a3t[ll+2] + cw3*a3t[ll+3];
      float xc = W1d*A1 + W2d*A2 + W3d*A3 + cbd;
      float sx = xc / (1.f + expf(-xc));
      sxt[d*129 + ll] = sx;
    }
  }
  __syncthreads();
  { // write silu(conv(x)) tile to global
    float* xs = ws + OFF_XS + (size_t)bq*64*1024;
    #pragma unroll
    for (int r = 0; r < 8; ++r){
      int fi = r*256 + t;
      int dd = fi >> 5, c4 = (fi & 31)*4;
      float4 v = make_float4(sxt[dd*129+c4], sxt[dd*129+c4+1],
                             sxt[dd*129+c4+2], sxt[dd*129+c4+3]);
      *(float4*)(xs + dd*1024 + l0 + c4) = v;
    }
  }
  { // xdb = xproj_w @ silu_x
    int l = t >> 1, kh = t & 1;
    float acc[10];
    #pragma unroll
    for (int kk = 0; kk < 10; ++kk) acc[kk] = 0.f;
    for (int dd = 0; dd < 64; ++dd){
      float v = sxt[dd*129 + l];
      #pragma unroll
      for (int kk = 0; kk < 10; ++kk) acc[kk] += xpw[(kh*10+kk)*64 + dd] * v;
    }
    #pragma unroll
    for (int kk = 0; kk < 10; ++kk) xdbt[l*20 + kh*10 + kk] = acc[kk];
  }
  __syncthreads();
  { // dt = softplus(dtlr @ dt_w.T + dt_b), write dt and B/C
    float w0 = dw[d*4+0], w1 = dw[d*4+1], w2 = dw[d*4+2], w3 = dw[d*4+3];
    float bd = dbv[d];
    float* dtg = ws + OFF_DT + ((size_t)bq*1024 + l0)*64;
    for (int j = 0; j < 32; ++j){
      int ll = lq*32 + j;
      float raw = bd + w0*xdbt[ll*20+0] + w1*xdbt[ll*20+1] + w2*xdbt[ll*20+2] + w3*xdbt[ll*20+3];
      float sp = fmaxf(raw, 0.f) + log1pf(expf(-fabsf(raw)));
      dtg[ll*64 + d] = sp;
    }
    float* bcg = ws + OFF_BC + ((size_t)bq*1024 + l0)*16;
    for (int idx = t; idx < 128*16; idx += 256){
      int ll = idx >> 4, k = idx & 15;
      bcg[ll*16 + k] = xdbt[ll*20 + 4 + k];
    }
  }
}

// ---------------- scan phase A: per-chunk (P,Q) ----------------
__global__ void __launch_bounds__(512) k_scanA(float* __restrict__ ws){
  int bi = blockIdx.x;                 // bq*32 + c
  int c = bi & 31, bq = bi >> 5, br = bq >> 4;
  int l0 = c * CLN;
  int t = threadIdx.x;
  int wv = t >> 6, lane = t & 63;
  int d = wv*8 + (lane >> 3), n = lane & 7;
  __shared__ float dtt[CLN*64];
  __shared__ float bct[CLN*16];
  __shared__ float xst[64*36];
  {
    const float* dtg = ws + OFF_DT + ((size_t)bq*1024 + l0)*64;
    ((float4*)dtt)[t] = ((const float4*)dtg)[t];
  }
  if (t < 128){
    const float* bcg = ws + OFF_BC + ((size_t)bq*1024 + l0)*16;
    ((float4*)bct)[t] = ((const float4*)bcg)[t];
  }
  {
    const float* xs = ws + OFF_XS + (size_t)bq*64*1024;
    int dd = t >> 3, q = t & 7;
    float4 v = *(const float4*)(xs + dd*1024 + l0 + q*4);
    *(float4*)(&xst[dd*36 + q*4]) = v;
  }
  float A2r = ws[OFF_AL2 + br*512 + t];
  __syncthreads();
  float P = 1.f, Q = 0.f;
  #pragma unroll 4
  for (int tt = 0; tt < CLN; ++tt){
    float dtv = dtt[tt*64 + d];
    float xv  = xst[d*36 + tt];
    float bv  = bct[tt*16 + n];
    float da  = exp2f(dtv * A2r);
    Q = fmaf(da, Q, dtv * bv * xv);
    P *= da;
  }
  ws[OFF_P + (size_t)bi*512 + t] = P;
  ws[OFF_Q + (size_t)bi*512 + t] = Q;
}

// ---------------- scan phase B: combine chunk summaries ----------------
__global__ void k_scanB(float* __restrict__ ws){
  int gid = blockIdx.x*256 + threadIdx.x;   // 0..16383
  int bq = gid >> 9, dn = gid & 511;
  size_t base = (size_t)bq*NCH*512 + dn;
  float h = 0.f;
  for (int c = 0; c < NCH; ++c){
    size_t idx = base + (size_t)c*512;
    ws[OFF_HIN + idx] = h;
    h = fmaf(ws[OFF_P + idx], h, ws[OFF_Q + idx]);
  }
}

// ---------------- scan phase C: replay + y, gate with silu(z), D*x ----------------
__global__ void __launch_bounds__(512) k_scanC(float* __restrict__ ws,
                                               const float* Dp, const float* Dp_b){
  int bi = blockIdx.x;
  int c = bi & 31, bq = bi >> 5, br = bq >> 4;
  int l0 = c * CLN;
  int t = threadIdx.x;
  int wv = t >> 6, lane = t & 63;
  int d = wv*8 + (lane >> 3), n = lane & 7;
  __shared__ float dtt[CLN*64];
  __shared__ float bct[CLN*16];
  __shared__ float xst[64*36];
  __shared__ float a1t[CLN], a2t[CLN];
  __shared__ float ylds[CLN*68];
  {
    const float* dtg = ws + OFF_DT + ((size_t)bq*1024 + l0)*64;
    ((float4*)dtt)[t] = ((const float4*)dtg)[t];
  }
  if (t < 128){
    const float* bcg = ws + OFF_BC + ((size_t)bq*1024 + l0)*16;
    ((float4*)bct)[t] = ((const float4*)bcg)[t];
  }
  {
    const float* xs = ws + OFF_XS + (size_t)bq*64*1024;
    int dd = t >> 3, q = t & 7;
    float4 v = *(const float4*)(xs + dd*1024 + l0 + q*4);
    *(float4*)(&xst[dd*36 + q*4]) = v;
  }
  if (t < CLN){
    a1t[t] = ws[OFF_SA1 + bq*1024 + l0 + t];
    a2t[t] = ws[OFF_SA2 + bq*1024 + l0 + t];
  }
  float A2r = ws[OFF_AL2 + br*512 + t];
  float h = ws[OFF_HIN + (size_t)bi*512 + t];
  const float* Dv = br ? Dp_b : Dp;
  float Dpd = Dv[d];
  float W1z = ws[OFF_W + br*384 +   0 + 64 + d];
  float W2z = ws[OFF_W + br*384 + 128 + 64 + d];
  float W3z = ws[OFF_W + br*384 + 256 + 64 + d];
  __syncthreads();
  #pragma unroll 4
  for (int tt = 0; tt < CLN; ++tt){
    float dtv = dtt[tt*64 + d];
    float xv  = xst[d*36 + tt];
    float bv  = bct[tt*16 + n];
    float cv  = bct[tt*16 + 8 + n];
    float da  = exp2f(dtv * A2r);
    h = fmaf(da, h, dtv * bv * xv);
    float pv = h * cv;
    pv += __shfl_xor(pv, 1, 64);
    pv += __shfl_xor(pv, 2, 64);
    pv += __shfl_xor(pv, 4, 64);
    if (n == 0){
      float y = pv + Dpd * xv;
      float zv = a1t[tt]*W1z + a2t[tt]*W2z + W3z;
      float g = zv / (1.f + expf(-zv));
      ylds[tt*68 + d] = y * g;
    }
  }
  __syncthreads();
  {
    float* yf = ws + OFF_YF + (size_t)bq*1024*64;
    int row = t >> 4, c4 = (t & 15)*4;
    int lglob = l0 + row;
    int lout = br ? (1023 - lglob) : lglob;
    float4 v = make_float4(ylds[row*68+c4], ylds[row*68+c4+1],
                           ylds[row*68+c4+2], ylds[row*68+c4+3]);
    *(float4*)(yf + (size_t)lout*64 + c4) = v;
  }
}

// ---------------- epilogue: rmsnorm + out_w + post + sigmoid ----------------
__global__ void k_epi(const float* norm_w, const float* out_w, const float* post_w,
                      const float* post_b, const float* __restrict__ ws,
                      float* __restrict__ out){
  int wv = threadIdx.x >> 6, lane = threadIdx.x & 63;
  int r = blockIdx.x*4 + wv;            // b*1024 + l
  const float* yf0 = ws + OFF_YF + (size_t)r*64;
  const float* yf1 = ws + OFF_YF + (size_t)16*1024*64 + (size_t)r*64;
  float v = yf0[lane] + yf1[lane];
  float ss = wave_rsum(v*v);
  float rstd = rsqrtf(ss*(1.f/64.f) + 1e-5f);
  float sn = v * rstd * norm_w[lane];
  float acc = 0.f;
  for (int dd = 0; dd < 64; ++dd){
    float snd = __shfl(sn, dd, 64);
    acc += out_w[lane*64 + dd] * snd;
  }
  float att = post_w[lane] * acc;
  att = wave_rsum(att);
  if (lane == 0) out[r] = 1.f / (1.f + expf(-(att + post_b[0])));
}

extern "C" void kernel_launch(void* const* d_in, const int* in_sizes, int n_in,
                              void* d_out, int out_size, void* d_ws, size_t ws_size,
                              hipStream_t stream){
  const float* img1      = (const float*)d_in[0];
  const float* img2      = (const float*)d_in[1];
  const float* pre_w     = (const float*)d_in[2];
  const float* pre_b     = (const float*)d_in[3];
  const float* ln_g      = (const float*)d_in[4];
  const float* ln_b      = (const float*)d_in[5];
  const float* in_w      = (const float*)d_in[6];
  const float* in_b_w    = (const float*)d_in[7];
  const float* conv_w    = (const float*)d_in[8];
  const float* conv_bias = (const float*)d_in[9];
  const float* convb_w   = (const float*)d_in[10];
  const float* convb_bias= (const float*)d_in[11];
  const float* xproj_w   = (const float*)d_in[12];
  const float* xprojb_w  = (const float*)d_in[13];
  const float* dt_w      = (const float*)d_in[14];
  const float* dt_bias   = (const float*)d_in[15];
  const float* dtb_w     = (const float*)d_in[16];
  const float* dtb_bias  = (const float*)d_in[17];
  const float* A_log     = (const float*)d_in[18];
  const float* A_b_log   = (const float*)d_in[19];
  const float* Dp        = (const float*)d_in[20];
  const float* Dp_b      = (const float*)d_in[21];
  const float* norm_w    = (const float*)d_in[22];
  const float* out_w     = (const float*)d_in[23];
  const float* post_w    = (const float*)d_in[24];
  const float* post_b    = (const float*)d_in[25];
  float* ws  = (float*)d_ws;
  float* out = (float*)d_out;

  k_consts<<<1, 256, 0, stream>>>(pre_w, pre_b, ln_g, ln_b, in_w, in_b_w, A_log, A_b_log, ws);
  k_pool<<<8192, 256, 0, stream>>>(img1, img2, ws);
  k_proj<<<256, 256, 0, stream>>>(conv_w, conv_bias, convb_w, convb_bias,
                                  xproj_w, xprojb_w, dt_w, dt_bias, dtb_w, dtb_bias, ws);
  k_scanA<<<1024, 512, 0, stream>>>(ws);
  k_scanB<<<64, 256, 0, stream>>>(ws);
  k_scanC<<<1024, 512, 0, stream>>>(ws, Dp, Dp_b);
  k_epi<<<4096, 256, 0, stream>>>(norm_w, out_w, post_w, post_b, ws, out);
}

// Round 2
// 110.838 us; speedup vs baseline: 1.2318x; 1.2318x over previous
//
#include <hip/hip_runtime.h>
#include <math.h>

#define NB 16
#define LL 1024
#define ND 64
#define NN 8
#define NCH 32   // scan chunks
#define CLN 32   // chunk length

// workspace float offsets
#define OFF_CONST 0          // 16
#define OFF_W     16         // [2][3][128] = 768
#define OFF_AL2   784        // [2][512] = 1024
#define OFF_SA1   1808       // [2][16][1024] = 32768
#define OFF_SA2   34576      // 32768
#define OFF_XS    67344      // [2*16][64][1024] = 2097152
#define OFF_DT    2164496    // [2*16][1024][64] = 2097152
#define OFF_BC    4261648    // [2*16][1024][16] = 524288
#define OFF_P     4785936    // [2*16][32][512] = 524288
#define OFF_Q     5310224    // 524288
#define OFF_HIN   5834512    // 524288
#define OFF_YF    6358800    // [2*16][1024][64] = 2097152
#define OFF_VE    8455952    // 64

__device__ __forceinline__ float wave_rsum(float v){
  #pragma unroll
  for (int o = 1; o < 64; o <<= 1) v += __shfl_xor(v, o, 64);
  return v;
}
__device__ __forceinline__ float wave_rmax(float v){
  #pragma unroll
  for (int o = 1; o < 64; o <<= 1) v = fmaxf(v, __shfl_xor(v, o, 64));
  return v;
}

// ---------------- consts: layernorm collapse vectors W1/W2/W3, A*log2e, veff2 ----------------
__global__ void k_consts(const float* pre_w, const float* pre_b, const float* ln_g,
                         const float* ln_b, const float* in_w, const float* in_b_w,
                         const float* A_log, const float* A_b_log,
                         const float* norm_w, const float* out_w, const float* post_w,
                         float* ws){
  __shared__ float gw[64], gb[64], lnbs[64];
  int t = threadIdx.x;
  if (t < 64){
    float w = pre_w[t], b = pre_b[t];
    float mw = wave_rsum(w) * (1.f/64.f);
    float mb = wave_rsum(b) * (1.f/64.f);
    float wc = w - mw, bc = b - mb;
    float Av = wave_rsum(wc*wc) * (1.f/64.f);
    float Bq = wave_rsum(wc*bc) * (1.f/64.f);
    float Cq = wave_rsum(bc*bc) * (1.f/64.f);
    gw[t] = wc * ln_g[t];
    gb[t] = bc * ln_g[t];
    lnbs[t] = ln_b[t];
    if (t == 0){ ws[OFF_CONST+0] = Av; ws[OFF_CONST+1] = Bq; ws[OFF_CONST+2] = Cq; }
  }
  __syncthreads();
  {
    int br = t >> 7, e = t & 127;
    const float* iw = br ? in_b_w : in_w;
    float s1 = 0.f, s2 = 0.f, s3 = 0.f;
    for (int d = 0; d < 64; ++d){
      float w = iw[e*64 + d];
      s1 += w * gw[d]; s2 += w * gb[d]; s3 += w * lnbs[d];
    }
    ws[OFF_W + br*384 +   0 + e] = s1;
    ws[OFF_W + br*384 + 128 + e] = s2;
    ws[OFF_W + br*384 + 256 + e] = s3;
  }
  for (int i = t; i < 1024; i += 256){
    int br = i >> 9, idx = i & 511;
    const float* al = br ? A_b_log : A_log;
    ws[OFF_AL2 + i] = -expf(al[idx]) * 1.4426950408889634f;
  }
  if (t < 64){
    // veff2[d] = norm_w[d] * sum_e post_w[e]*out_w[e,d]  (epilogue collapse)
    float s = 0.f;
    for (int e = 0; e < 64; ++e) s += post_w[e] * out_w[e*64 + t];
    ws[OFF_VE + t] = s * norm_w[t];
  }
}

// ---------------- pool: max over HxW; 4 rows per wave, deep load pipeline ----------------
__global__ void __launch_bounds__(256) k_pool(const float* __restrict__ img1,
                                              const float* __restrict__ img2,
                                              float* __restrict__ ws){
  int wv = threadIdx.x >> 6, lane = threadIdx.x & 63;
  int r0 = (blockIdx.x * 4 + wv) * 4;     // 4 consecutive rows, same img, same b
  int img = r0 >> 14;
  int rem0 = r0 & 16383;                  // b*1024 + l0
  const float* src = (img ? img2 : img1) + (size_t)rem0 * 1024;
  float4 v[4][4];
  #pragma unroll
  for (int r = 0; r < 4; ++r){
    #pragma unroll
    for (int it = 0; it < 4; ++it)
      v[r][it] = ((const float4*)(src + (size_t)r*1024))[it*64 + lane];
  }
  float Av = ws[OFF_CONST], Bq = ws[OFF_CONST+1], Cq = ws[OFF_CONST+2];
  float mr[4];
  #pragma unroll
  for (int r = 0; r < 4; ++r){
    float m = -INFINITY;
    #pragma unroll
    for (int it = 0; it < 4; ++it){
      float4 q = v[r][it];
      m = fmaxf(m, fmaxf(fmaxf(q.x, q.y), fmaxf(q.z, q.w)));
    }
    mr[r] = wave_rmax(m);
  }
  if (lane < 4){
    float m = mr[0];
    #pragma unroll
    for (int r = 1; r < 4; ++r) if (lane == r) m = mr[r];   // static indices only
    float var = m*m*Av + 2.f*m*Bq + Cq;
    float inv = rsqrtf(var + 1e-5f);
    int b = rem0 >> 10, l = (rem0 & 1023) + lane;
    int pos = img ? ((16 + b)*1024 + (1023 - l)) : (rem0 + lane);  // branch1 pre-reversed
    ws[OFF_SA1 + pos] = m * inv;
    ws[OFF_SA2 + pos] = inv;
  }
}

// ---------------- conv+silu (x), xproj, dt ----------------
__global__ void k_proj(const float* conv_w, const float* conv_b,
                       const float* convb_w, const float* convb_b,
                       const float* xproj_w, const float* xprojb_w,
                       const float* dt_w, const float* dt_b,
                       const float* dtb_w, const float* dtb_b,
                       float* __restrict__ ws){
  int bi = blockIdx.x;            // 2*16*8
  int chunk = bi & 7, bq = bi >> 3;
  int br = bq >> 4;
  int l0 = chunk * 128;
  int t = threadIdx.x;
  __shared__ float a1t[132], a2t[132], a3t[132];
  __shared__ float sxt[64*129];
  __shared__ float xdbt[128*20];
  const float* cw  = br ? convb_w : conv_w;
  const float* cb  = br ? convb_b : conv_b;
  const float* xpw = br ? xprojb_w : xproj_w;
  const float* dw  = br ? dtb_w : dt_w;
  const float* dbv = br ? dtb_b : dt_b;
  for (int i = t; i < 131; i += 256){
    int gl = l0 - 3 + i;
    bool ok = gl >= 0;
    a1t[i] = ok ? ws[OFF_SA1 + bq*1024 + gl] : 0.f;
    a2t[i] = ok ? ws[OFF_SA2 + bq*1024 + gl] : 0.f;
    a3t[i] = ok ? 1.f : 0.f;
  }
  __syncthreads();
  int d = t & 63, lq = t >> 6;
  {
    float cw0 = cw[d*4+0], cw1 = cw[d*4+1], cw2 = cw[d*4+2], cw3 = cw[d*4+3];
    float cbd = cb[d];
    float W1d = ws[OFF_W + br*384 + d];
    float W2d = ws[OFF_W + br*384 + 128 + d];
    float W3d = ws[OFF_W + br*384 + 256 + d];
    for (int j = 0; j < 32; ++j){
      int ll = lq*32 + j;
      float A1 = cw0*a1t[ll] + cw1*a1t[ll+1] + cw2*a1t[ll+2] + cw3*a1t[ll+3];
      float A2 = cw0*a2t[ll] + cw1*a2t[ll+1] + cw2*a2t[ll+2] + cw3*a2t[ll+3];
      float A3 = cw0*a3t[ll] + cw1*a3t[ll+1] + cw2*a3t[ll+2] + cw3*a3t[ll+3];
      float xc = W1d*A1 + W2d*A2 + W3d*A3 + cbd;
      float sx = xc / (1.f + expf(-xc));
      sxt[d*129 + ll] = sx;
    }
  }
  __syncthreads();
  { // write silu(conv(x)) tile to global
    float* xs = ws + OFF_XS + (size_t)bq*64*1024;
    #pragma unroll
    for (int r = 0; r < 8; ++r){
      int fi = r*256 + t;
      int dd = fi >> 5, c4 = (fi & 31)*4;
      float4 v = make_float4(sxt[dd*129+c4], sxt[dd*129+c4+1],
                             sxt[dd*129+c4+2], sxt[dd*129+c4+3]);
      *(float4*)(xs + dd*1024 + l0 + c4) = v;
    }
  }
  { // xdb = xproj_w @ silu_x
    int l = t >> 1, kh = t & 1;
    float acc[10];
    #pragma unroll
    for (int kk = 0; kk < 10; ++kk) acc[kk] = 0.f;
    for (int dd = 0; dd < 64; ++dd){
      float v = sxt[dd*129 + l];
      #pragma unroll
      for (int kk = 0; kk < 10; ++kk) acc[kk] += xpw[(kh*10+kk)*64 + dd] * v;
    }
    #pragma unroll
    for (int kk = 0; kk < 10; ++kk) xdbt[l*20 + kh*10 + kk] = acc[kk];
  }
  __syncthreads();
  { // dt = softplus(dtlr @ dt_w.T + dt_b), write dt and B/C
    float w0 = dw[d*4+0], w1 = dw[d*4+1], w2 = dw[d*4+2], w3 = dw[d*4+3];
    float bd = dbv[d];
    float* dtg = ws + OFF_DT + ((size_t)bq*1024 + l0)*64;
    for (int j = 0; j < 32; ++j){
      int ll = lq*32 + j;
      float raw = bd + w0*xdbt[ll*20+0] + w1*xdbt[ll*20+1] + w2*xdbt[ll*20+2] + w3*xdbt[ll*20+3];
      float sp = fmaxf(raw, 0.f) + log1pf(expf(-fabsf(raw)));
      dtg[ll*64 + d] = sp;
    }
    float* bcg = ws + OFF_BC + ((size_t)bq*1024 + l0)*16;
    for (int idx = t; idx < 128*16; idx += 256){
      int ll = idx >> 4, k = idx & 15;
      bcg[ll*16 + k] = xdbt[ll*20 + 4 + k];
    }
  }
}

// ---------------- scan phase A: per-chunk (P,Q) ----------------
__global__ void __launch_bounds__(512) k_scanA(float* __restrict__ ws){
  int bi = blockIdx.x;                 // bq*32 + c
  int c = bi & 31, bq = bi >> 5, br = bq >> 4;
  int l0 = c * CLN;
  int t = threadIdx.x;
  int wv = t >> 6, lane = t & 63;
  int d = wv*8 + (lane >> 3), n = lane & 7;
  __shared__ float dtt[CLN*64];
  __shared__ float bct[CLN*16];
  __shared__ float xst[64*36];
  {
    const float* dtg = ws + OFF_DT + ((size_t)bq*1024 + l0)*64;
    ((float4*)dtt)[t] = ((const float4*)dtg)[t];
  }
  if (t < 128){
    const float* bcg = ws + OFF_BC + ((size_t)bq*1024 + l0)*16;
    ((float4*)bct)[t] = ((const float4*)bcg)[t];
  }
  {
    const float* xs = ws + OFF_XS + (size_t)bq*64*1024;
    int dd = t >> 3, q = t & 7;
    float4 v = *(const float4*)(xs + dd*1024 + l0 + q*4);
    *(float4*)(&xst[dd*36 + q*4]) = v;
  }
  float A2r = ws[OFF_AL2 + br*512 + t];
  __syncthreads();
  float P = 1.f, Q = 0.f;
  #pragma unroll 4
  for (int tt = 0; tt < CLN; ++tt){
    float dtv = dtt[tt*64 + d];
    float xv  = xst[d*36 + tt];
    float bv  = bct[tt*16 + n];
    float da  = exp2f(dtv * A2r);
    Q = fmaf(da, Q, dtv * bv * xv);
    P *= da;
  }
  ws[OFF_P + (size_t)bi*512 + t] = P;
  ws[OFF_Q + (size_t)bi*512 + t] = Q;
}

// ---------------- scan phase B: combine chunk summaries (register prefetch) ----------------
__global__ void __launch_bounds__(64) k_scanB(float* __restrict__ ws){
  int gid = blockIdx.x*64 + threadIdx.x;   // 0..16383
  int bq = gid >> 9, dn = gid & 511;
  size_t base = (size_t)bq*NCH*512 + dn;
  float P[NCH], Q[NCH];
  #pragma unroll
  for (int c = 0; c < NCH; ++c){
    P[c] = ws[OFF_P + base + (size_t)c*512];
    Q[c] = ws[OFF_Q + base + (size_t)c*512];
  }
  float h = 0.f;
  #pragma unroll
  for (int c = 0; c < NCH; ++c){
    ws[OFF_HIN + base + (size_t)c*512] = h;
    h = fmaf(P[c], h, Q[c]);
  }
}

// ---------------- scan phase C: replay + y, gate with silu(z), D*x ----------------
__global__ void __launch_bounds__(512) k_scanC(float* __restrict__ ws,
                                               const float* Dp, const float* Dp_b){
  int bi = blockIdx.x;
  int c = bi & 31, bq = bi >> 5, br = bq >> 4;
  int l0 = c * CLN;
  int t = threadIdx.x;
  int wv = t >> 6, lane = t & 63;
  int d = wv*8 + (lane >> 3), n = lane & 7;
  __shared__ float dtt[CLN*64];
  __shared__ float bct[CLN*16];
  __shared__ float xst[64*36];
  __shared__ float a1t[CLN], a2t[CLN];
  __shared__ float ylds[CLN*68];
  {
    const float* dtg = ws + OFF_DT + ((size_t)bq*1024 + l0)*64;
    ((float4*)dtt)[t] = ((const float4*)dtg)[t];
  }
  if (t < 128){
    const float* bcg = ws + OFF_BC + ((size_t)bq*1024 + l0)*16;
    ((float4*)bct)[t] = ((const float4*)bcg)[t];
  }
  {
    const float* xs = ws + OFF_XS + (size_t)bq*64*1024;
    int dd = t >> 3, q = t & 7;
    float4 v = *(const float4*)(xs + dd*1024 + l0 + q*4);
    *(float4*)(&xst[dd*36 + q*4]) = v;
  }
  if (t < CLN){
    a1t[t] = ws[OFF_SA1 + bq*1024 + l0 + t];
    a2t[t] = ws[OFF_SA2 + bq*1024 + l0 + t];
  }
  float A2r = ws[OFF_AL2 + br*512 + t];
  float h = ws[OFF_HIN + (size_t)bi*512 + t];
  const float* Dv = br ? Dp_b : Dp;
  float Dpd = Dv[d];
  float W1z = ws[OFF_W + br*384 +   0 + 64 + d];
  float W2z = ws[OFF_W + br*384 + 128 + 64 + d];
  float W3z = ws[OFF_W + br*384 + 256 + 64 + d];
  __syncthreads();
  #pragma unroll 4
  for (int tt = 0; tt < CLN; ++tt){
    float dtv = dtt[tt*64 + d];
    float xv  = xst[d*36 + tt];
    float bv  = bct[tt*16 + n];
    float cv  = bct[tt*16 + 8 + n];
    float da  = exp2f(dtv * A2r);
    h = fmaf(da, h, dtv * bv * xv);
    float pv = h * cv;
    pv += __shfl_xor(pv, 1, 64);
    pv += __shfl_xor(pv, 2, 64);
    pv += __shfl_xor(pv, 4, 64);
    if (n == 0){
      float y = pv + Dpd * xv;
      float zv = a1t[tt]*W1z + a2t[tt]*W2z + W3z;
      float g = zv / (1.f + expf(-zv));
      ylds[tt*68 + d] = y * g;
    }
  }
  __syncthreads();
  {
    float* yf = ws + OFF_YF + (size_t)bq*1024*64;
    int row = t >> 4, c4 = (t & 15)*4;
    int lglob = l0 + row;
    int lout = br ? (1023 - lglob) : lglob;
    float4 v = make_float4(ylds[row*68+c4], ylds[row*68+c4+1],
                           ylds[row*68+c4+2], ylds[row*68+c4+3]);
    *(float4*)(yf + (size_t)lout*64 + c4) = v;
  }
}

// ---------------- epilogue: rmsnorm + collapsed matvec + sigmoid ----------------
__global__ void __launch_bounds__(256) k_epi(const float* post_b,
                                             const float* __restrict__ ws,
                                             float* __restrict__ out){
  int wv = threadIdx.x >> 6, lane = threadIdx.x & 63;
  int r0 = (blockIdx.x*4 + wv)*4;        // 4 rows per wave
  float ve = ws[OFF_VE + lane];
  float pb = post_b[0];
  float va[4];
  #pragma unroll
  for (int r = 0; r < 4; ++r){
    size_t row = (size_t)(r0 + r);
    va[r] = ws[OFF_YF + row*64 + lane] +
            ws[OFF_YF + (size_t)16*1024*64 + row*64 + lane];
  }
  #pragma unroll
  for (int r = 0; r < 4; ++r){
    float v = va[r];
    float ss = v*v, dp = v*ve;
    #pragma unroll
    for (int o = 1; o < 64; o <<= 1){
      ss += __shfl_xor(ss, o, 64);
      dp += __shfl_xor(dp, o, 64);
    }
    if (lane == 0){
      float rstd = rsqrtf(ss*(1.f/64.f) + 1e-5f);
      float att = dp * rstd + pb;
      out[r0 + r] = 1.f / (1.f + expf(-att));
    }
  }
}

extern "C" void kernel_launch(void* const* d_in, const int* in_sizes, int n_in,
                              void* d_out, int out_size, void* d_ws, size_t ws_size,
                              hipStream_t stream){
  const float* img1      = (const float*)d_in[0];
  const float* img2      = (const float*)d_in[1];
  const float* pre_w     = (const float*)d_in[2];
  const float* pre_b     = (const float*)d_in[3];
  const float* ln_g      = (const float*)d_in[4];
  const float* ln_b      = (const float*)d_in[5];
  const float* in_w      = (const float*)d_in[6];
  const float* in_b_w    = (const float*)d_in[7];
  const float* conv_w    = (const float*)d_in[8];
  const float* conv_bias = (const float*)d_in[9];
  const float* convb_w   = (const float*)d_in[10];
  const float* convb_bias= (const float*)d_in[11];
  const float* xproj_w   = (const float*)d_in[12];
  const float* xprojb_w  = (const float*)d_in[13];
  const float* dt_w      = (const float*)d_in[14];
  const float* dt_bias   = (const float*)d_in[15];
  const float* dtb_w     = (const float*)d_in[16];
  const float* dtb_bias  = (const float*)d_in[17];
  const float* A_log     = (const float*)d_in[18];
  const float* A_b_log   = (const float*)d_in[19];
  const float* Dp        = (const float*)d_in[20];
  const float* Dp_b      = (const float*)d_in[21];
  const float* norm_w    = (const float*)d_in[22];
  const float* out_w     = (const float*)d_in[23];
  const float* post_w    = (const float*)d_in[24];
  const float* post_b    = (const float*)d_in[25];
  float* ws  = (float*)d_ws;
  float* out = (float*)d_out;

  k_consts<<<1, 256, 0, stream>>>(pre_w, pre_b, ln_g, ln_b, in_w, in_b_w,
                                  A_log, A_b_log, norm_w, out_w, post_w, ws);
  k_pool<<<2048, 256, 0, stream>>>(img1, img2, ws);
  k_proj<<<256, 256, 0, stream>>>(conv_w, conv_bias, convb_w, convb_bias,
                                  xproj_w, xprojb_w, dt_w, dt_bias, dtb_w, dtb_bias, ws);
  k_scanA<<<1024, 512, 0, stream>>>(ws);
  k_scanB<<<256, 64, 0, stream>>>(ws);
  k_scanC<<<1024, 512, 0, stream>>>(ws, Dp, Dp_b);
  k_epi<<<1024, 256, 0, stream>>>(post_b, ws, out);
}

// Round 3
// 89.707 us; speedup vs baseline: 1.5220x; 1.2356x over previous
//
#include <hip/hip_runtime.h>
#include <math.h>

typedef float f32x4 __attribute__((ext_vector_type(4)));

#define NCH 32   // scan chunks
#define CLN 32   // chunk length
#define NPOOLB 1024

// workspace float offsets (total ~6.2 MB)
#define OFF_CONST 0          // 16
#define OFF_W     16         // [2][3][128] = 768
#define OFF_AL2   784        // [2][512] = 1024
#define OFF_VE    1808       // 64
#define OFF_SA    1872       // [2*16][1024] raw max = 32768
#define OFF_P     34640      // [2*16][32][512] = 524288
#define OFF_Q     558928     // 524288
#define OFF_HIN   1083216    // 524288

__device__ __forceinline__ float wave_rsum(float v){
  #pragma unroll
  for (int o = 1; o < 64; o <<= 1) v += __shfl_xor(v, o, 64);
  return v;
}
__device__ __forceinline__ float wave_rmax(float v){
  #pragma unroll
  for (int o = 1; o < 64; o <<= 1) v = fmaxf(v, __shfl_xor(v, o, 64));
  return v;
}

// ---------------- pool (persistent, nt loads) + consts (block NPOOLB) ----------------
__global__ void __launch_bounds__(256) k_pool(
    const float* __restrict__ img1, const float* __restrict__ img2,
    const float* pre_w, const float* pre_b, const float* ln_g, const float* ln_b,
    const float* in_w, const float* in_b_w, const float* A_log, const float* A_b_log,
    const float* norm_w, const float* out_w, const float* post_w,
    float* __restrict__ ws){
  int t = threadIdx.x;
  if (blockIdx.x == NPOOLB){
    // ---- consts ----
    __shared__ float gw[64], gb[64], lnbs[64];
    if (t < 64){
      float w = pre_w[t], b = pre_b[t];
      float mw = wave_rsum(w) * (1.f/64.f);
      float mb = wave_rsum(b) * (1.f/64.f);
      float wc = w - mw, bc = b - mb;
      float Av = wave_rsum(wc*wc) * (1.f/64.f);
      float Bq = wave_rsum(wc*bc) * (1.f/64.f);
      float Cq = wave_rsum(bc*bc) * (1.f/64.f);
      gw[t] = wc * ln_g[t];
      gb[t] = bc * ln_g[t];
      lnbs[t] = ln_b[t];
      if (t == 0){ ws[OFF_CONST+0] = Av; ws[OFF_CONST+1] = Bq; ws[OFF_CONST+2] = Cq; }
    }
    __syncthreads();
    {
      int br = t >> 7, e = t & 127;
      const float* iw = br ? in_b_w : in_w;
      float s1 = 0.f, s2 = 0.f, s3 = 0.f;
      for (int d = 0; d < 64; ++d){
        float w = iw[e*64 + d];
        s1 += w * gw[d]; s2 += w * gb[d]; s3 += w * lnbs[d];
      }
      ws[OFF_W + br*384 +   0 + e] = s1;
      ws[OFF_W + br*384 + 128 + e] = s2;
      ws[OFF_W + br*384 + 256 + e] = s3;
    }
    for (int i = t; i < 1024; i += 256){
      int br = i >> 9, idx = i & 511;
      const float* al = br ? A_b_log : A_log;
      ws[OFF_AL2 + i] = -expf(al[idx]) * 1.4426950408889634f;
    }
    if (t < 64){
      float s = 0.f;
      for (int e = 0; e < 64; ++e) s += post_w[e] * out_w[e*64 + t];
      ws[OFF_VE + t] = s * norm_w[t];
    }
    return;
  }
  // ---- pool: 8 rows per wave, 2-row pipeline, non-temporal reads ----
  int wv = t >> 6, lane = t & 63;
  int wid = blockIdx.x * 4 + wv;          // 0..4095
  int r0 = wid * 8;                       // 8 consecutive rows, same img, same b
  int img = r0 >> 14;
  int rem0 = r0 & 16383;                  // b*1024 + l0
  const float* base = (img ? img2 : img1) + (size_t)rem0 * 1024;
  const f32x4* p = (const f32x4*)base + lane;   // row stride = 256 f32x4
  f32x4 cur0, cur1, cur2, cur3, nx0, nx1, nx2, nx3;
  cur0 = __builtin_nontemporal_load(p +   0);
  cur1 = __builtin_nontemporal_load(p +  64);
  cur2 = __builtin_nontemporal_load(p + 128);
  cur3 = __builtin_nontemporal_load(p + 192);
  float mkeep = 0.f;
  #pragma unroll
  for (int r = 0; r < 8; ++r){
    if (r < 7){
      const f32x4* q = p + (r+1)*256;
      nx0 = __builtin_nontemporal_load(q +   0);
      nx1 = __builtin_nontemporal_load(q +  64);
      nx2 = __builtin_nontemporal_load(q + 128);
      nx3 = __builtin_nontemporal_load(q + 192);
    }
    f32x4 a, b;
    a.x = fmaxf(cur0.x, cur1.x); a.y = fmaxf(cur0.y, cur1.y);
    a.z = fmaxf(cur0.z, cur1.z); a.w = fmaxf(cur0.w, cur1.w);
    b.x = fmaxf(cur2.x, cur3.x); b.y = fmaxf(cur2.y, cur3.y);
    b.z = fmaxf(cur2.z, cur3.z); b.w = fmaxf(cur2.w, cur3.w);
    float m = fmaxf(fmaxf(fmaxf(a.x,b.x), fmaxf(a.y,b.y)),
                    fmaxf(fmaxf(a.z,b.z), fmaxf(a.w,b.w)));
    m = wave_rmax(m);
    if (lane == r) mkeep = m;
    cur0 = nx0; cur1 = nx1; cur2 = nx2; cur3 = nx3;
  }
  if (lane < 8){
    int b2 = rem0 >> 10, l = (rem0 & 1023) + lane;
    int pos = img ? ((16 + b2)*1024 + (1023 - l)) : (rem0 + lane);  // branch1 pre-reversed
    ws[OFF_SA + pos] = mkeep;
  }
}

// ---------------- shared proj scratch ----------------
struct Smem {
  float a1[36], a2[36], a3[36];
  float xpt[20*65];     // padded stride 65 (bank-conflict-free)
  float dtlr[32*4];
  float sxt[64*37];     // [d][ll] stride 37
  float dtt[32*64];     // [ll][d]
  float bct[32*16];     // [ll][k]
};

// recompute conv+silu+xproj+dt for one chunk into LDS (from pooled scalars only)
__device__ __forceinline__ void proj_chunk(
    int bq, int c, int br,
    const float* __restrict__ cw, const float* __restrict__ cb,
    const float* __restrict__ xpw, const float* __restrict__ dw,
    const float* __restrict__ dbv,
    const float* __restrict__ ws, Smem& S, int t){
  __syncthreads();                 // protect S from prior readers
  if (t < 36){
    int gl = c*CLN - 3 + t;
    bool ok = (gl >= 0) && (t < 35);
    float m = ok ? ws[OFF_SA + bq*1024 + gl] : 0.f;
    float Av = ws[OFF_CONST], Bq = ws[OFF_CONST+1], Cq = ws[OFF_CONST+2];
    float inv = rsqrtf(m*m*Av + 2.f*m*Bq + Cq + 1e-5f);
    S.a1[t] = ok ? m*inv : 0.f;
    S.a2[t] = ok ? inv   : 0.f;
    S.a3[t] = ok ? 1.f   : 0.f;
  }
  for (int i = t; i < 20*64; i += 512){
    int k = i >> 6, d = i & 63;
    S.xpt[k*65 + d] = xpw[i];
  }
  __syncthreads();
  {
    int d = t & 63, lq = t >> 6;
    float cw0=cw[d*4], cw1=cw[d*4+1], cw2=cw[d*4+2], cw3=cw[d*4+3];
    float cbd = cb[d];
    float W1d = ws[OFF_W + br*384 + d];
    float W2d = ws[OFF_W + br*384 + 128 + d];
    float W3d = ws[OFF_W + br*384 + 256 + d];
    #pragma unroll
    for (int j = 0; j < 4; ++j){
      int ll = lq*4 + j;
      float A1 = cw0*S.a1[ll] + cw1*S.a1[ll+1] + cw2*S.a1[ll+2] + cw3*S.a1[ll+3];
      float A2 = cw0*S.a2[ll] + cw1*S.a2[ll+1] + cw2*S.a2[ll+2] + cw3*S.a2[ll+3];
      float A3 = cw0*S.a3[ll] + cw1*S.a3[ll+1] + cw2*S.a3[ll+2] + cw3*S.a3[ll+3];
      float xc = W1d*A1 + W2d*A2 + W3d*A3 + cbd;
      S.sxt[d*37 + ll] = xc / (1.f + expf(-xc));
    }
  }
  __syncthreads();
  {
    int ll = t >> 4, k = t & 15;
    float acc = 0.f;
    #pragma unroll 8
    for (int d = 0; d < 64; ++d) acc += S.xpt[(4+k)*65 + d] * S.sxt[d*37 + ll];
    S.bct[ll*16 + k] = acc;
  }
  if (t < 128){
    int ll = t >> 2, r = t & 3;
    float acc = 0.f;
    #pragma unroll 8
    for (int d = 0; d < 64; ++d) acc += S.xpt[r*65 + d] * S.sxt[d*37 + ll];
    S.dtlr[ll*4 + r] = acc;
  }
  __syncthreads();
  {
    int d = t & 63, lq = t >> 6;
    float w0=dw[d*4], w1=dw[d*4+1], w2=dw[d*4+2], w3=dw[d*4+3];
    float bd = dbv[d];
    #pragma unroll
    for (int j = 0; j < 4; ++j){
      int ll = lq*4 + j;
      float raw = bd + w0*S.dtlr[ll*4] + w1*S.dtlr[ll*4+1]
                     + w2*S.dtlr[ll*4+2] + w3*S.dtlr[ll*4+3];
      S.dtt[ll*64 + d] = fmaxf(raw, 0.f) + log1pf(expf(-fabsf(raw)));
    }
  }
  __syncthreads();
}

// ---------------- K2: proj + scan phase A (per-chunk P,Q) ----------------
__global__ void __launch_bounds__(512) k_projA(
    const float* conv_w, const float* conv_b, const float* convb_w, const float* convb_b,
    const float* xproj_w, const float* xprojb_w,
    const float* dt_w, const float* dt_b, const float* dtb_w, const float* dtb_b,
    float* __restrict__ ws){
  __shared__ Smem S;
  int bi = blockIdx.x;                 // bq*32 + c
  int c = bi & 31, bq = bi >> 5, br = bq >> 4;
  int t = threadIdx.x;
  proj_chunk(bq, c, br,
             br ? convb_w : conv_w,  br ? convb_b : conv_b,
             br ? xprojb_w : xproj_w, br ? dtb_w : dt_w, br ? dtb_b : dt_b,
             ws, S, t);
  int lane = t & 63, wv = t >> 6;
  int d = wv*8 + (lane >> 3), n = lane & 7;
  float A2r = ws[OFF_AL2 + br*512 + t];
  float P = 1.f, Q = 0.f;
  #pragma unroll 4
  for (int tt = 0; tt < CLN; ++tt){
    float dtv = S.dtt[tt*64 + d];
    float xv  = S.sxt[d*37 + tt];
    float bv  = S.bct[tt*16 + n];
    float da  = exp2f(dtv * A2r);
    Q = fmaf(da, Q, dtv * bv * xv);
    P *= da;
  }
  ws[OFF_P + (size_t)bi*512 + t] = P;
  ws[OFF_Q + (size_t)bi*512 + t] = Q;
}

// ---------------- K3: combine chunk summaries ----------------
__global__ void __launch_bounds__(64) k_scanB(float* __restrict__ ws){
  int gid = blockIdx.x*64 + threadIdx.x;   // 0..16383
  int bq = gid >> 9, dn = gid & 511;
  size_t base = (size_t)bq*NCH*512 + dn;
  float P[NCH], Q[NCH];
  #pragma unroll
  for (int c = 0; c < NCH; ++c){
    P[c] = ws[OFF_P + base + (size_t)c*512];
    Q[c] = ws[OFF_Q + base + (size_t)c*512];
  }
  float h = 0.f;
  #pragma unroll
  for (int c = 0; c < NCH; ++c){
    ws[OFF_HIN + base + (size_t)c*512] = h;
    h = fmaf(P[c], h, Q[c]);
  }
}

// ---------------- K4: proj + scan C fwd & bwd + gate + rmsnorm + out ----------------
__global__ void __launch_bounds__(512) k_projC(
    const float* conv_w, const float* conv_b, const float* convb_w, const float* convb_b,
    const float* xproj_w, const float* xprojb_w,
    const float* dt_w, const float* dt_b, const float* dtb_w, const float* dtb_b,
    const float* Dp, const float* Dp_b, const float* post_b,
    float* __restrict__ ws, float* __restrict__ out){
  __shared__ Smem S;
  __shared__ float ylds[CLN*65];
  int bi = blockIdx.x;                 // b*32 + c (output tile)
  int c = bi & 31, b = bi >> 5;
  int t = threadIdx.x;
  int lane = t & 63, wv = t >> 6;
  int d = wv*8 + (lane >> 3), n = lane & 7;
  #pragma unroll
  for (int pass = 0; pass < 2; ++pass){
    int bq = pass ? b + 16 : b;
    int ch = pass ? 31 - c : c;
    int br = pass;
    proj_chunk(bq, ch, br,
               pass ? convb_w : conv_w,  pass ? convb_b : conv_b,
               pass ? xprojb_w : xproj_w, pass ? dtb_w : dt_w, pass ? dtb_b : dt_b,
               ws, S, t);
    float A2r = ws[OFF_AL2 + br*512 + t];
    float h   = ws[OFF_HIN + (size_t)(bq*NCH + ch)*512 + t];
    float Dpd = (pass ? Dp_b : Dp)[d];
    float W1z = ws[OFF_W + br*384 +   0 + 64 + d];
    float W2z = ws[OFF_W + br*384 + 128 + 64 + d];
    float W3z = ws[OFF_W + br*384 + 256 + 64 + d];
    #pragma unroll 4
    for (int tt = 0; tt < CLN; ++tt){
      float dtv = S.dtt[tt*64 + d];
      float xv  = S.sxt[d*37 + tt];
      float bv  = S.bct[tt*16 + n];
      float cv  = S.bct[tt*16 + 8 + n];
      float da  = exp2f(dtv * A2r);
      h = fmaf(da, h, dtv * bv * xv);
      float pv = h * cv;
      pv += __shfl_xor(pv, 1, 64);
      pv += __shfl_xor(pv, 2, 64);
      pv += __shfl_xor(pv, 4, 64);
      if (n == 0){
        float y = pv + Dpd * xv;
        float zv = S.a1[tt+3]*W1z + S.a2[tt+3]*W2z + W3z;
        float g = zv / (1.f + expf(-zv));
        int row = pass ? (31 - tt) : tt;
        if (pass == 0) ylds[row*65 + d] = y * g;
        else           ylds[row*65 + d] += y * g;
      }
    }
  }
  __syncthreads();
  // epilogue: rmsnorm + collapsed matvec + sigmoid; 8 waves x 4 rows
  float ve = ws[OFF_VE + lane];
  float pb = post_b[0];
  #pragma unroll
  for (int j = 0; j < 4; ++j){
    int row = wv*4 + j;
    float v = ylds[row*65 + lane];
    float ss = v*v, dp = v*ve;
    #pragma unroll
    for (int o = 1; o < 64; o <<= 1){
      ss += __shfl_xor(ss, o, 64);
      dp += __shfl_xor(dp, o, 64);
    }
    if (lane == 0){
      float rstd = rsqrtf(ss*(1.f/64.f) + 1e-5f);
      out[b*1024 + c*CLN + row] = 1.f / (1.f + expf(-(dp*rstd + pb)));
    }
  }
}

extern "C" void kernel_launch(void* const* d_in, const int* in_sizes, int n_in,
                              void* d_out, int out_size, void* d_ws, size_t ws_size,
                              hipStream_t stream){
  const float* img1      = (const float*)d_in[0];
  const float* img2      = (const float*)d_in[1];
  const float* pre_w     = (const float*)d_in[2];
  const float* pre_b     = (const float*)d_in[3];
  const float* ln_g      = (const float*)d_in[4];
  const float* ln_b      = (const float*)d_in[5];
  const float* in_w      = (const float*)d_in[6];
  const float* in_b_w    = (const float*)d_in[7];
  const float* conv_w    = (const float*)d_in[8];
  const float* conv_bias = (const float*)d_in[9];
  const float* convb_w   = (const float*)d_in[10];
  const float* convb_bias= (const float*)d_in[11];
  const float* xproj_w   = (const float*)d_in[12];
  const float* xprojb_w  = (const float*)d_in[13];
  const float* dt_w      = (const float*)d_in[14];
  const float* dt_bias   = (const float*)d_in[15];
  const float* dtb_w     = (const float*)d_in[16];
  const float* dtb_bias  = (const float*)d_in[17];
  const float* A_log     = (const float*)d_in[18];
  const float* A_b_log   = (const float*)d_in[19];
  const float* Dp        = (const float*)d_in[20];
  const float* Dp_b      = (const float*)d_in[21];
  const float* norm_w    = (const float*)d_in[22];
  const float* out_w     = (const float*)d_in[23];
  const float* post_w    = (const float*)d_in[24];
  const float* post_b    = (const float*)d_in[25];
  float* ws  = (float*)d_ws;
  float* out = (float*)d_out;

  k_pool<<<NPOOLB+1, 256, 0, stream>>>(img1, img2, pre_w, pre_b, ln_g, ln_b,
                                       in_w, in_b_w, A_log, A_b_log,
                                       norm_w, out_w, post_w, ws);
  k_projA<<<1024, 512, 0, stream>>>(conv_w, conv_bias, convb_w, convb_bias,
                                    xproj_w, xprojb_w, dt_w, dt_bias, dtb_w, dtb_bias, ws);
  k_scanB<<<256, 64, 0, stream>>>(ws);
  k_projC<<<512, 512, 0, stream>>>(conv_w, conv_bias, convb_w, convb_bias,
                                   xproj_w, xprojb_w, dt_w, dt_bias, dtb_w, dtb_bias,
                                   Dp, Dp_b, post_b, ws, out);
}

// Round 5
// 77.654 us; speedup vs baseline: 1.7582x; 1.1552x over previous
//
#include <hip/hip_runtime.h>
#include <math.h>

typedef float f32x4 __attribute__((ext_vector_type(4)));

#define NCH 32   // scan chunks
#define CLN 32   // chunk length
#define NPOOLB 1024

// workspace float offsets (total ~14.8 MB)
#define OFF_CONST 0          // 16
#define OFF_W     16         // [2][3][128] = 768
#define OFF_AL2   784        // [2][512] = 1024
#define OFF_VE    1808       // 64
#define OFF_SA    1872       // [2*16][1024] raw max = 32768
#define OFF_P     34640      // [2*16][32][512] = 524288
#define OFF_Q     558928     // 524288
#define OFF_HIN   1083216    // 524288
#define OFF_YF    1607504    // [2*16][1024][64] = 2097152

#define LOG2E 1.4426950408889634f
#define LN2   0.6931471805599453f

__device__ __forceinline__ float fexp2(float x){ return __builtin_amdgcn_exp2f(x); }
__device__ __forceinline__ float flog2(float x){ return __builtin_amdgcn_logf(x); }
__device__ __forceinline__ float frcp (float x){ return __builtin_amdgcn_rcpf(x); }
__device__ __forceinline__ float fsigmoid(float x){ return frcp(1.f + fexp2(-x*LOG2E)); }
__device__ __forceinline__ float fsilu(float x){ return x * fsigmoid(x); }
__device__ __forceinline__ float fsoftplus(float x){
  return fmaxf(x, 0.f) + LN2 * flog2(1.f + fexp2(-fabsf(x)*LOG2E));
}

__device__ __forceinline__ float wave_rsum(float v){
  #pragma unroll
  for (int o = 1; o < 64; o <<= 1) v += __shfl_xor(v, o, 64);
  return v;
}
__device__ __forceinline__ float wave_rmax(float v){
  #pragma unroll
  for (int o = 1; o < 64; o <<= 1) v = fmaxf(v, __shfl_xor(v, o, 64));
  return v;
}

// ---------------- pool (persistent, nt loads) + consts (block NPOOLB) ----------------
__global__ void __launch_bounds__(256) k_pool(
    const float* __restrict__ img1, const float* __restrict__ img2,
    const float* pre_w, const float* pre_b, const float* ln_g, const float* ln_b,
    const float* in_w, const float* in_b_w, const float* A_log, const float* A_b_log,
    const float* norm_w, const float* out_w, const float* post_w,
    float* __restrict__ ws){
  int t = threadIdx.x;
  if (blockIdx.x == NPOOLB){
    // ---- consts ----
    __shared__ float gw[64], gb[64], lnbs[64];
    if (t < 64){
      float w = pre_w[t], b = pre_b[t];
      float mw = wave_rsum(w) * (1.f/64.f);
      float mb = wave_rsum(b) * (1.f/64.f);
      float wc = w - mw, bc = b - mb;
      float Av = wave_rsum(wc*wc) * (1.f/64.f);
      float Bq = wave_rsum(wc*bc) * (1.f/64.f);
      float Cq = wave_rsum(bc*bc) * (1.f/64.f);
      gw[t] = wc * ln_g[t];
      gb[t] = bc * ln_g[t];
      lnbs[t] = ln_b[t];
      if (t == 0){ ws[OFF_CONST+0] = Av; ws[OFF_CONST+1] = Bq; ws[OFF_CONST+2] = Cq; }
    }
    __syncthreads();
    {
      int br = t >> 7, e = t & 127;
      const float* iw = br ? in_b_w : in_w;
      float s1 = 0.f, s2 = 0.f, s3 = 0.f;
      for (int d = 0; d < 64; ++d){
        float w = iw[e*64 + d];
        s1 += w * gw[d]; s2 += w * gb[d]; s3 += w * lnbs[d];
      }
      ws[OFF_W + br*384 +   0 + e] = s1;
      ws[OFF_W + br*384 + 128 + e] = s2;
      ws[OFF_W + br*384 + 256 + e] = s3;
    }
    for (int i = t; i < 1024; i += 256){
      int br = i >> 9, idx = i & 511;
      const float* al = br ? A_b_log : A_log;
      ws[OFF_AL2 + i] = -expf(al[idx]) * LOG2E;
    }
    if (t < 64){
      float s = 0.f;
      for (int e = 0; e < 64; ++e) s += post_w[e] * out_w[e*64 + t];
      ws[OFF_VE + t] = s * norm_w[t];
    }
    return;
  }
  // ---- pool: 8 rows per wave, 2-row pipeline, non-temporal reads ----
  int wv = t >> 6, lane = t & 63;
  int wid = blockIdx.x * 4 + wv;          // 0..4095
  int r0 = wid * 8;                       // 8 consecutive rows, same img, same b
  int img = r0 >> 14;
  int rem0 = r0 & 16383;                  // b*1024 + l0
  const float* base = (img ? img2 : img1) + (size_t)rem0 * 1024;
  const f32x4* p = (const f32x4*)base + lane;   // row stride = 256 f32x4
  f32x4 cur0, cur1, cur2, cur3, nx0, nx1, nx2, nx3;
  cur0 = __builtin_nontemporal_load(p +   0);
  cur1 = __builtin_nontemporal_load(p +  64);
  cur2 = __builtin_nontemporal_load(p + 128);
  cur3 = __builtin_nontemporal_load(p + 192);
  float mkeep = 0.f;
  #pragma unroll
  for (int r = 0; r < 8; ++r){
    if (r < 7){
      const f32x4* q = p + (r+1)*256;
      nx0 = __builtin_nontemporal_load(q +   0);
      nx1 = __builtin_nontemporal_load(q +  64);
      nx2 = __builtin_nontemporal_load(q + 128);
      nx3 = __builtin_nontemporal_load(q + 192);
    }
    f32x4 a, b;
    a.x = fmaxf(cur0.x, cur1.x); a.y = fmaxf(cur0.y, cur1.y);
    a.z = fmaxf(cur0.z, cur1.z); a.w = fmaxf(cur0.w, cur1.w);
    b.x = fmaxf(cur2.x, cur3.x); b.y = fmaxf(cur2.y, cur3.y);
    b.z = fmaxf(cur2.z, cur3.z); b.w = fmaxf(cur2.w, cur3.w);
    float m = fmaxf(fmaxf(fmaxf(a.x,b.x), fmaxf(a.y,b.y)),
                    fmaxf(fmaxf(a.z,b.z), fmaxf(a.w,b.w)));
    m = wave_rmax(m);
    if (lane == r) mkeep = m;
    cur0 = nx0; cur1 = nx1; cur2 = nx2; cur3 = nx3;
  }
  if (lane < 8){
    int b2 = rem0 >> 10, l = (rem0 & 1023) + lane;
    int pos = img ? ((16 + b2)*1024 + (1023 - l)) : (rem0 + lane);  // branch1 pre-reversed
    ws[OFF_SA + pos] = mkeep;
  }
}

// ---------------- shared proj scratch ----------------
struct Smem {
  float a1[36], a2[36], a3[36];
  float xpt[20*65];     // padded stride 65 (bank-conflict-free)
  float dtlr[32*4];
  float sxt[64*37];     // [d][ll] stride 37
  float dtt[32*64];     // [ll][d]
  float bct[32*16];     // [ll][k]
};

// recompute conv+silu+xproj+dt for one chunk into LDS (from pooled scalars only)
__device__ __forceinline__ void proj_chunk(
    int bq, int c, int br,
    const float* __restrict__ cw, const float* __restrict__ cb,
    const float* __restrict__ xpw, const float* __restrict__ dw,
    const float* __restrict__ dbv,
    const float* __restrict__ ws, Smem& S, int t){
  __syncthreads();                 // protect S from prior readers
  if (t < 36){
    int gl = c*CLN - 3 + t;
    bool ok = (gl >= 0) && (t < 35);
    float m = ok ? ws[OFF_SA + bq*1024 + gl] : 0.f;
    float Av = ws[OFF_CONST], Bq = ws[OFF_CONST+1], Cq = ws[OFF_CONST+2];
    float inv = rsqrtf(m*m*Av + 2.f*m*Bq + Cq + 1e-5f);
    S.a1[t] = ok ? m*inv : 0.f;
    S.a2[t] = ok ? inv   : 0.f;
    S.a3[t] = ok ? 1.f   : 0.f;
  }
  for (int i = t; i < 20*64; i += 512){
    int k = i >> 6, d = i & 63;
    S.xpt[k*65 + d] = xpw[i];
  }
  __syncthreads();
  {
    int d = t & 63, lq = t >> 6;
    float cw0=cw[d*4], cw1=cw[d*4+1], cw2=cw[d*4+2], cw3=cw[d*4+3];
    float cbd = cb[d];
    float W1d = ws[OFF_W + br*384 + d];
    float W2d = ws[OFF_W + br*384 + 128 + d];
    float W3d = ws[OFF_W + br*384 + 256 + d];
    #pragma unroll
    for (int j = 0; j < 4; ++j){
      int ll = lq*4 + j;
      float A1 = cw0*S.a1[ll] + cw1*S.a1[ll+1] + cw2*S.a1[ll+2] + cw3*S.a1[ll+3];
      float A2 = cw0*S.a2[ll] + cw1*S.a2[ll+1] + cw2*S.a2[ll+2] + cw3*S.a2[ll+3];
      float A3 = cw0*S.a3[ll] + cw1*S.a3[ll+1] + cw2*S.a3[ll+2] + cw3*S.a3[ll+3];
      float xc = W1d*A1 + W2d*A2 + W3d*A3 + cbd;
      S.sxt[d*37 + ll] = fsilu(xc);
    }
  }
  __syncthreads();
  {
    int ll = t >> 4, k = t & 15;
    float acc = 0.f;
    #pragma unroll 8
    for (int d = 0; d < 64; ++d) acc += S.xpt[(4+k)*65 + d] * S.sxt[d*37 + ll];
    S.bct[ll*16 + k] = acc;
  }
  if (t < 128){
    int ll = t >> 2, r = t & 3;
    float acc = 0.f;
    #pragma unroll 8
    for (int d = 0; d < 64; ++d) acc += S.xpt[r*65 + d] * S.sxt[d*37 + ll];
    S.dtlr[ll*4 + r] = acc;
  }
  __syncthreads();
  {
    int d = t & 63, lq = t >> 6;
    float w0=dw[d*4], w1=dw[d*4+1], w2=dw[d*4+2], w3=dw[d*4+3];
    float bd = dbv[d];
    #pragma unroll
    for (int j = 0; j < 4; ++j){
      int ll = lq*4 + j;
      float raw = bd + w0*S.dtlr[ll*4] + w1*S.dtlr[ll*4+1]
                     + w2*S.dtlr[ll*4+2] + w3*S.dtlr[ll*4+3];
      S.dtt[ll*64 + d] = fsoftplus(raw);
    }
  }
  __syncthreads();
}

// ---------------- K2: proj + scan phase A (per-chunk P,Q) ----------------
__global__ void __launch_bounds__(512) k_projA(
    const float* conv_w, const float* conv_b, const float* convb_w, const float* convb_b,
    const float* xproj_w, const float* xprojb_w,
    const float* dt_w, const float* dt_b, const float* dtb_w, const float* dtb_b,
    float* __restrict__ ws){
  __shared__ Smem S;
  int bi = blockIdx.x;                 // bq*32 + c
  int c = bi & 31, bq = bi >> 5, br = bq >> 4;
  int t = threadIdx.x;
  proj_chunk(bq, c, br,
             br ? convb_w : conv_w,  br ? convb_b : conv_b,
             br ? xprojb_w : xproj_w, br ? dtb_w : dt_w, br ? dtb_b : dt_b,
             ws, S, t);
  int lane = t & 63, wv = t >> 6;
  int d = wv*8 + (lane >> 3), n = lane & 7;
  float A2r = ws[OFF_AL2 + br*512 + t];
  float P = 1.f, Q = 0.f;
  #pragma unroll 4
  for (int tt = 0; tt < CLN; ++tt){
    float dtv = S.dtt[tt*64 + d];
    float xv  = S.sxt[d*37 + tt];
    float bv  = S.bct[tt*16 + n];
    float da  = fexp2(dtv * A2r);
    Q = fmaf(da, Q, dtv * bv * xv);
    P *= da;
  }
  ws[OFF_P + (size_t)bi*512 + t] = P;
  ws[OFF_Q + (size_t)bi*512 + t] = Q;
}

// ---------------- K3: combine chunk summaries ----------------
__global__ void __launch_bounds__(64) k_scanB(float* __restrict__ ws){
  int gid = blockIdx.x*64 + threadIdx.x;   // 0..16383
  int bq = gid >> 9, dn = gid & 511;
  size_t base = (size_t)bq*NCH*512 + dn;
  float P[NCH], Q[NCH];
  #pragma unroll
  for (int c = 0; c < NCH; ++c){
    P[c] = ws[OFF_P + base + (size_t)c*512];
    Q[c] = ws[OFF_Q + base + (size_t)c*512];
  }
  float h = 0.f;
  #pragma unroll
  for (int c = 0; c < NCH; ++c){
    ws[OFF_HIN + base + (size_t)c*512] = h;
    h = fmaf(P[c], h, Q[c]);
  }
}

// ---------------- K4: proj + replay scan + gate -> YF (one pass per block) ----------------
__global__ void __launch_bounds__(512) k_projY(
    const float* conv_w, const float* conv_b, const float* convb_w, const float* convb_b,
    const float* xproj_w, const float* xprojb_w,
    const float* dt_w, const float* dt_b, const float* dtb_w, const float* dtb_b,
    const float* Dp, const float* Dp_b,
    float* __restrict__ ws){
  __shared__ Smem S;
  __shared__ float ylds[CLN*65];
  int bi = blockIdx.x;                 // br*512 + b*32 + ch
  int br = bi >> 9, rem = bi & 511, b = rem >> 5, ch = rem & 31;
  int bq = br*16 + b;
  int t = threadIdx.x;
  int lane = t & 63, wv = t >> 6;
  int d = wv*8 + (lane >> 3), n = lane & 7;
  proj_chunk(bq, ch, br,
             br ? convb_w : conv_w,  br ? convb_b : conv_b,
             br ? xprojb_w : xproj_w, br ? dtb_w : dt_w, br ? dtb_b : dt_b,
             ws, S, t);
  float A2r = ws[OFF_AL2 + br*512 + t];
  float h   = ws[OFF_HIN + (size_t)(bq*NCH + ch)*512 + t];
  float Dpd = (br ? Dp_b : Dp)[d];
  float W1z = ws[OFF_W + br*384 +   0 + 64 + d];
  float W2z = ws[OFF_W + br*384 + 128 + 64 + d];
  float W3z = ws[OFF_W + br*384 + 256 + 64 + d];
  #pragma unroll 4
  for (int tt = 0; tt < CLN; ++tt){
    float dtv = S.dtt[tt*64 + d];
    float xv  = S.sxt[d*37 + tt];
    float bv  = S.bct[tt*16 + n];
    float cv  = S.bct[tt*16 + 8 + n];
    float da  = fexp2(dtv * A2r);
    h = fmaf(da, h, dtv * bv * xv);
    float pv = h * cv;
    pv += __shfl_xor(pv, 1, 64);
    pv += __shfl_xor(pv, 2, 64);
    pv += __shfl_xor(pv, 4, 64);
    if (n == 0){
      float y = pv + Dpd * xv;
      float zv = S.a1[tt+3]*W1z + S.a2[tt+3]*W2z + W3z;
      float g = fsilu(zv);           // silu(z) = z*sigmoid(z) — the round-4 bug was sigmoid-only
      int row = br ? (31 - tt) : tt;
      ylds[row*65 + d] = y * g;
    }
  }
  __syncthreads();
  {
    float* yf = ws + OFF_YF + (size_t)bq*1024*64;
    int otile = br ? (31 - ch) : ch;
    int row = t >> 4, c4 = (t & 15)*4;
    f32x4 v;
    v.x = ylds[row*65+c4]; v.y = ylds[row*65+c4+1];
    v.z = ylds[row*65+c4+2]; v.w = ylds[row*65+c4+3];
    *(f32x4*)(yf + ((size_t)otile*32 + row)*64 + c4) = v;
  }
}

// ---------------- K5: epilogue: rmsnorm + collapsed matvec + sigmoid ----------------
__global__ void __launch_bounds__(256) k_epi(const float* post_b,
                                             const float* __restrict__ ws,
                                             float* __restrict__ out){
  int wv = threadIdx.x >> 6, lane = threadIdx.x & 63;
  int r0 = (blockIdx.x*4 + wv)*4;        // 4 rows per wave
  float ve = ws[OFF_VE + lane];
  float pb = post_b[0];
  float va[4];
  #pragma unroll
  for (int r = 0; r < 4; ++r){
    size_t row = (size_t)(r0 + r);
    va[r] = ws[OFF_YF + row*64 + lane] +
            ws[OFF_YF + (size_t)16*1024*64 + row*64 + lane];
  }
  #pragma unroll
  for (int r = 0; r < 4; ++r){
    float v = va[r];
    float ss = v*v, dp = v*ve;
    #pragma unroll
    for (int o = 1; o < 64; o <<= 1){
      ss += __shfl_xor(ss, o, 64);
      dp += __shfl_xor(dp, o, 64);
    }
    if (lane == 0){
      float rstd = rsqrtf(ss*(1.f/64.f) + 1e-5f);
      out[r0 + r] = fsigmoid(dp*rstd + pb);
    }
  }
}

extern "C" void kernel_launch(void* const* d_in, const int* in_sizes, int n_in,
                              void* d_out, int out_size, void* d_ws, size_t ws_size,
                              hipStream_t stream){
  const float* img1      = (const float*)d_in[0];
  const float* img2      = (const float*)d_in[1];
  const float* pre_w     = (const float*)d_in[2];
  const float* pre_b     = (const float*)d_in[3];
  const float* ln_g      = (const float*)d_in[4];
  const float* ln_b      = (const float*)d_in[5];
  const float* in_w      = (const float*)d_in[6];
  const float* in_b_w    = (const float*)d_in[7];
  const float* conv_w    = (const float*)d_in[8];
  const float* conv_bias = (const float*)d_in[9];
  const float* convb_w   = (const float*)d_in[10];
  const float* convb_bias= (const float*)d_in[11];
  const float* xproj_w   = (const float*)d_in[12];
  const float* xprojb_w  = (const float*)d_in[13];
  const float* dt_w      = (const float*)d_in[14];
  const float* dt_bias   = (const float*)d_in[15];
  const float* dtb_w     = (const float*)d_in[16];
  const float* dtb_bias  = (const float*)d_in[17];
  const float* A_log     = (const float*)d_in[18];
  const float* A_b_log   = (const float*)d_in[19];
  const float* Dp        = (const float*)d_in[20];
  const float* Dp_b      = (const float*)d_in[21];
  const float* norm_w    = (const float*)d_in[22];
  const float* out_w     = (const float*)d_in[23];
  const float* post_w    = (const float*)d_in[24];
  const float* post_b    = (const float*)d_in[25];
  float* ws  = (float*)d_ws;
  float* out = (float*)d_out;

  k_pool<<<NPOOLB+1, 256, 0, stream>>>(img1, img2, pre_w, pre_b, ln_g, ln_b,
                                       in_w, in_b_w, A_log, A_b_log,
                                       norm_w, out_w, post_w, ws);
  k_projA<<<1024, 512, 0, stream>>>(conv_w, conv_bias, convb_w, convb_bias,
                                    xproj_w, xprojb_w, dt_w, dt_bias, dtb_w, dtb_bias, ws);
  k_scanB<<<256, 64, 0, stream>>>(ws);
  k_projY<<<1024, 512, 0, stream>>>(conv_w, conv_bias, convb_w, convb_bias,
                                    xproj_w, xprojb_w, dt_w, dt_bias, dtb_w, dtb_bias,
                                    Dp, Dp_b, ws);
  k_epi<<<1024, 256, 0, stream>>>(post_b, ws, out);
}

// Round 6
// 74.837 us; speedup vs baseline: 1.8244x; 1.0376x over previous
//
#include <hip/hip_runtime.h>
#include <math.h>

typedef float f32x4 __attribute__((ext_vector_type(4)));

#define NCH 32   // scan chunks
#define CLN 32   // chunk length
#define NPOOLB 1024

// workspace float offsets (~6.4 MB)
#define OFF_CONST 0          // 16
#define OFF_W     16         // [2][3][128] = 768
#define OFF_AL2   784        // [2][512] = 1024
#define OFF_VE    1808       // 64
#define OFF_SA    1872       // [2*16][1024] raw max = 32768
#define OFF_P     34640      // [2*16][32][512] = 524288
#define OFF_Q     558928     // 524288
#define OFF_HIN   1083216    // 524288

#define LOG2E 1.4426950408889634f
#define LN2   0.6931471805599453f

__device__ __forceinline__ float fexp2(float x){ return __builtin_amdgcn_exp2f(x); }
__device__ __forceinline__ float flog2(float x){ return __builtin_amdgcn_logf(x); }
__device__ __forceinline__ float frcp (float x){ return __builtin_amdgcn_rcpf(x); }
__device__ __forceinline__ float fsigmoid(float x){ return frcp(1.f + fexp2(-x*LOG2E)); }
__device__ __forceinline__ float fsilu(float x){ return x * fsigmoid(x); }
__device__ __forceinline__ float fsoftplus(float x){
  return fmaxf(x, 0.f) + LN2 * flog2(1.f + fexp2(-fabsf(x)*LOG2E));
}

__device__ __forceinline__ float wave_rsum(float v){
  #pragma unroll
  for (int o = 1; o < 64; o <<= 1) v += __shfl_xor(v, o, 64);
  return v;
}
__device__ __forceinline__ float wave_rmax(float v){
  #pragma unroll
  for (int o = 1; o < 64; o <<= 1) v = fmaxf(v, __shfl_xor(v, o, 64));
  return v;
}

// ---------------- pool (persistent, nt loads, 3-row-deep prefetch) + consts ----------------
__global__ void __launch_bounds__(256) k_pool(
    const float* __restrict__ img1, const float* __restrict__ img2,
    const float* pre_w, const float* pre_b, const float* ln_g, const float* ln_b,
    const float* in_w, const float* in_b_w, const float* A_log, const float* A_b_log,
    const float* norm_w, const float* out_w, const float* post_w,
    float* __restrict__ ws){
  int t = threadIdx.x;
  if (blockIdx.x == NPOOLB){
    // ---- consts ----
    __shared__ float gw[64], gb[64], lnbs[64];
    if (t < 64){
      float w = pre_w[t], b = pre_b[t];
      float mw = wave_rsum(w) * (1.f/64.f);
      float mb = wave_rsum(b) * (1.f/64.f);
      float wc = w - mw, bc = b - mb;
      float Av = wave_rsum(wc*wc) * (1.f/64.f);
      float Bq = wave_rsum(wc*bc) * (1.f/64.f);
      float Cq = wave_rsum(bc*bc) * (1.f/64.f);
      gw[t] = wc * ln_g[t];
      gb[t] = bc * ln_g[t];
      lnbs[t] = ln_b[t];
      if (t == 0){ ws[OFF_CONST+0] = Av; ws[OFF_CONST+1] = Bq; ws[OFF_CONST+2] = Cq; }
    }
    __syncthreads();
    {
      int br = t >> 7, e = t & 127;
      const float* iw = br ? in_b_w : in_w;
      float s1 = 0.f, s2 = 0.f, s3 = 0.f;
      for (int d = 0; d < 64; ++d){
        float w = iw[e*64 + d];
        s1 += w * gw[d]; s2 += w * gb[d]; s3 += w * lnbs[d];
      }
      ws[OFF_W + br*384 +   0 + e] = s1;
      ws[OFF_W + br*384 + 128 + e] = s2;
      ws[OFF_W + br*384 + 256 + e] = s3;
    }
    for (int i = t; i < 1024; i += 256){
      int br = i >> 9, idx = i & 511;
      const float* al = br ? A_b_log : A_log;
      ws[OFF_AL2 + i] = -expf(al[idx]) * LOG2E;
    }
    if (t < 64){
      float s = 0.f;
      for (int e = 0; e < 64; ++e) s += post_w[e] * out_w[e*64 + t];
      ws[OFF_VE + t] = s * norm_w[t];
    }
    return;
  }
  // ---- pool: 8 rows per wave, 3-row lookahead (12 nt loads in flight) ----
  int wv = t >> 6, lane = t & 63;
  int wid = blockIdx.x * 4 + wv;          // 0..4095
  int r0 = wid * 8;                       // 8 consecutive rows, same img, same b
  int img = r0 >> 14;
  int rem0 = r0 & 16383;                  // b*1024 + l0
  const float* base = (img ? img2 : img1) + (size_t)rem0 * 1024;
  const f32x4* p = (const f32x4*)base + lane;   // row stride = 256 f32x4
  f32x4 v0[4], v1[4], v2[4];
  #pragma unroll
  for (int i = 0; i < 4; ++i) v0[i] = __builtin_nontemporal_load(p +   0 + i*64);
  #pragma unroll
  for (int i = 0; i < 4; ++i) v1[i] = __builtin_nontemporal_load(p + 256 + i*64);
  #pragma unroll
  for (int i = 0; i < 4; ++i) v2[i] = __builtin_nontemporal_load(p + 512 + i*64);
  float mkeep = 0.f;
  #pragma unroll
  for (int r = 0; r < 8; ++r){
    float m = -INFINITY;
    #pragma unroll
    for (int i = 0; i < 4; ++i){
      f32x4 q = v0[i];
      m = fmaxf(m, fmaxf(fmaxf(q.x, q.y), fmaxf(q.z, q.w)));
    }
    m = wave_rmax(m);
    if (lane == r) mkeep = m;
    #pragma unroll
    for (int i = 0; i < 4; ++i){ v0[i] = v1[i]; v1[i] = v2[i]; }
    if (r < 5){
      const f32x4* q = p + (r+3)*256;
      #pragma unroll
      for (int i = 0; i < 4; ++i) v2[i] = __builtin_nontemporal_load(q + i*64);
    }
  }
  if (lane < 8){
    int b2 = rem0 >> 10, l = (rem0 & 1023) + lane;
    int pos = img ? ((16 + b2)*1024 + (1023 - l)) : (rem0 + lane);  // branch1 pre-reversed
    ws[OFF_SA + pos] = mkeep;
  }
}

// ---------------- shared proj scratch ----------------
struct Smem {
  float a1[36], a2[36], a3[36];
  float xpt[20*65];     // padded stride 65 (bank-conflict-free)
  float dtlr[32*4];
  float sxt[64*37];     // [d][ll] stride 37
  float dtt[32*64];     // [ll][d]
  float bct[32*16];     // [ll][k]
};

// recompute conv+silu+xproj+dt for one chunk into LDS (from pooled scalars only)
__device__ __forceinline__ void proj_chunk(
    int bq, int c, int br,
    const float* __restrict__ cw, const float* __restrict__ cb,
    const float* __restrict__ xpw, const float* __restrict__ dw,
    const float* __restrict__ dbv,
    const float* __restrict__ ws, Smem& S, int t){
  __syncthreads();                 // protect S from prior readers
  if (t < 36){
    int gl = c*CLN - 3 + t;
    bool ok = (gl >= 0) && (t < 35);
    float m = ok ? ws[OFF_SA + bq*1024 + gl] : 0.f;
    float Av = ws[OFF_CONST], Bq = ws[OFF_CONST+1], Cq = ws[OFF_CONST+2];
    float inv = rsqrtf(m*m*Av + 2.f*m*Bq + Cq + 1e-5f);
    S.a1[t] = ok ? m*inv : 0.f;
    S.a2[t] = ok ? inv   : 0.f;
    S.a3[t] = ok ? 1.f   : 0.f;
  }
  for (int i = t; i < 20*64; i += 512){
    int k = i >> 6, d = i & 63;
    S.xpt[k*65 + d] = xpw[i];
  }
  __syncthreads();
  {
    int d = t & 63, lq = t >> 6;
    float cw0=cw[d*4], cw1=cw[d*4+1], cw2=cw[d*4+2], cw3=cw[d*4+3];
    float cbd = cb[d];
    float W1d = ws[OFF_W + br*384 + d];
    float W2d = ws[OFF_W + br*384 + 128 + d];
    float W3d = ws[OFF_W + br*384 + 256 + d];
    #pragma unroll
    for (int j = 0; j < 4; ++j){
      int ll = lq*4 + j;
      float A1 = cw0*S.a1[ll] + cw1*S.a1[ll+1] + cw2*S.a1[ll+2] + cw3*S.a1[ll+3];
      float A2 = cw0*S.a2[ll] + cw1*S.a2[ll+1] + cw2*S.a2[ll+2] + cw3*S.a2[ll+3];
      float A3 = cw0*S.a3[ll] + cw1*S.a3[ll+1] + cw2*S.a3[ll+2] + cw3*S.a3[ll+3];
      float xc = W1d*A1 + W2d*A2 + W3d*A3 + cbd;
      S.sxt[d*37 + ll] = fsilu(xc);
    }
  }
  __syncthreads();
  {
    int ll = t >> 4, k = t & 15;
    float acc = 0.f;
    #pragma unroll 8
    for (int d = 0; d < 64; ++d) acc += S.xpt[(4+k)*65 + d] * S.sxt[d*37 + ll];
    S.bct[ll*16 + k] = acc;
  }
  if (t < 128){
    int ll = t >> 2, r = t & 3;
    float acc = 0.f;
    #pragma unroll 8
    for (int d = 0; d < 64; ++d) acc += S.xpt[r*65 + d] * S.sxt[d*37 + ll];
    S.dtlr[ll*4 + r] = acc;
  }
  __syncthreads();
  {
    int d = t & 63, lq = t >> 6;
    float w0=dw[d*4], w1=dw[d*4+1], w2=dw[d*4+2], w3=dw[d*4+3];
    float bd = dbv[d];
    #pragma unroll
    for (int j = 0; j < 4; ++j){
      int ll = lq*4 + j;
      float raw = bd + w0*S.dtlr[ll*4] + w1*S.dtlr[ll*4+1]
                     + w2*S.dtlr[ll*4+2] + w3*S.dtlr[ll*4+3];
      S.dtt[ll*64 + d] = fsoftplus(raw);
    }
  }
  __syncthreads();
}

// ---------------- K2: proj + scan phase A (per-chunk P,Q) ----------------
__global__ void __launch_bounds__(512) k_projA(
    const float* conv_w, const float* conv_b, const float* convb_w, const float* convb_b,
    const float* xproj_w, const float* xprojb_w,
    const float* dt_w, const float* dt_b, const float* dtb_w, const float* dtb_b,
    float* __restrict__ ws){
  __shared__ Smem S;
  int bi = blockIdx.x;                 // bq*32 + c
  int c = bi & 31, bq = bi >> 5, br = bq >> 4;
  int t = threadIdx.x;
  proj_chunk(bq, c, br,
             br ? convb_w : conv_w,  br ? convb_b : conv_b,
             br ? xprojb_w : xproj_w, br ? dtb_w : dt_w, br ? dtb_b : dt_b,
             ws, S, t);
  int lane = t & 63, wv = t >> 6;
  int d = wv*8 + (lane >> 3), n = lane & 7;
  float A2r = ws[OFF_AL2 + br*512 + t];
  float P = 1.f, Q = 0.f;
  #pragma unroll 4
  for (int tt = 0; tt < CLN; ++tt){
    float dtv = S.dtt[tt*64 + d];
    float xv  = S.sxt[d*37 + tt];
    float bv  = S.bct[tt*16 + n];
    float da  = fexp2(dtv * A2r);
    Q = fmaf(da, Q, dtv * bv * xv);
    P *= da;
  }
  ws[OFF_P + (size_t)bi*512 + t] = P;
  ws[OFF_Q + (size_t)bi*512 + t] = Q;
}

// ---------------- K3: combine chunk summaries ----------------
__global__ void __launch_bounds__(64) k_scanB(float* __restrict__ ws){
  int gid = blockIdx.x*64 + threadIdx.x;   // 0..16383
  int bq = gid >> 9, dn = gid & 511;
  size_t base = (size_t)bq*NCH*512 + dn;
  float P[NCH], Q[NCH];
  #pragma unroll
  for (int c = 0; c < NCH; ++c){
    P[c] = ws[OFF_P + base + (size_t)c*512];
    Q[c] = ws[OFF_Q + base + (size_t)c*512];
  }
  float h = 0.f;
  #pragma unroll
  for (int c = 0; c < NCH; ++c){
    ws[OFF_HIN + base + (size_t)c*512] = h;
    h = fmaf(P[c], h, Q[c]);
  }
}

// ---------------- K4: proj + replay fwd & bwd + gate + rmsnorm + out ----------------
__global__ void __launch_bounds__(512) k_projC(
    const float* conv_w, const float* conv_b, const float* convb_w, const float* convb_b,
    const float* xproj_w, const float* xprojb_w,
    const float* dt_w, const float* dt_b, const float* dtb_w, const float* dtb_b,
    const float* Dp, const float* Dp_b, const float* post_b,
    float* __restrict__ ws, float* __restrict__ out){
  __shared__ Smem S;
  __shared__ float ylds[CLN*65];
  int bi = blockIdx.x;                 // b*32 + c (output tile)
  int c = bi & 31, b = bi >> 5;
  int t = threadIdx.x;
  int lane = t & 63, wv = t >> 6;
  int d = wv*8 + (lane >> 3), n = lane & 7;
  #pragma unroll
  for (int pass = 0; pass < 2; ++pass){
    int bq = pass ? b + 16 : b;
    int ch = pass ? 31 - c : c;
    int br = pass;
    proj_chunk(bq, ch, br,
               pass ? convb_w : conv_w,  pass ? convb_b : conv_b,
               pass ? xprojb_w : xproj_w, pass ? dtb_w : dt_w, pass ? dtb_b : dt_b,
               ws, S, t);
    float A2r = ws[OFF_AL2 + br*512 + t];
    float h   = ws[OFF_HIN + (size_t)(bq*NCH + ch)*512 + t];
    float Dpd = (pass ? Dp_b : Dp)[d];
    float W1z = ws[OFF_W + br*384 +   0 + 64 + d];
    float W2z = ws[OFF_W + br*384 + 128 + 64 + d];
    float W3z = ws[OFF_W + br*384 + 256 + 64 + d];
    #pragma unroll 4
    for (int tt = 0; tt < CLN; ++tt){
      float dtv = S.dtt[tt*64 + d];
      float xv  = S.sxt[d*37 + tt];
      float bv  = S.bct[tt*16 + n];
      float cv  = S.bct[tt*16 + 8 + n];
      float da  = fexp2(dtv * A2r);
      h = fmaf(da, h, dtv * bv * xv);
      float pv = h * cv;
      pv += __shfl_xor(pv, 1, 64);
      pv += __shfl_xor(pv, 2, 64);
      pv += __shfl_xor(pv, 4, 64);
      if (n == 0){
        float y = pv + Dpd * xv;
        float zv = S.a1[tt+3]*W1z + S.a2[tt+3]*W2z + W3z;
        float g = fsilu(zv);         // silu(z) = z*sigmoid(z)
        int row = pass ? (31 - tt) : tt;
        if (pass == 0) ylds[row*65 + d] = y * g;
        else           ylds[row*65 + d] += y * g;
      }
    }
  }
  __syncthreads();
  // epilogue: rmsnorm + collapsed matvec + sigmoid; 8 waves x 4 rows
  float ve = ws[OFF_VE + lane];
  float pb = post_b[0];
  #pragma unroll
  for (int j = 0; j < 4; ++j){
    int row = wv*4 + j;
    float v = ylds[row*65 + lane];
    float ss = v*v, dp = v*ve;
    #pragma unroll
    for (int o = 1; o < 64; o <<= 1){
      ss += __shfl_xor(ss, o, 64);
      dp += __shfl_xor(dp, o, 64);
    }
    if (lane == 0){
      float rstd = rsqrtf(ss*(1.f/64.f) + 1e-5f);
      out[b*1024 + c*CLN + row] = fsigmoid(dp*rstd + pb);
    }
  }
}

extern "C" void kernel_launch(void* const* d_in, const int* in_sizes, int n_in,
                              void* d_out, int out_size, void* d_ws, size_t ws_size,
                              hipStream_t stream){
  const float* img1      = (const float*)d_in[0];
  const float* img2      = (const float*)d_in[1];
  const float* pre_w     = (const float*)d_in[2];
  const float* pre_b     = (const float*)d_in[3];
  const float* ln_g      = (const float*)d_in[4];
  const float* ln_b      = (const float*)d_in[5];
  const float* in_w      = (const float*)d_in[6];
  const float* in_b_w    = (const float*)d_in[7];
  const float* conv_w    = (const float*)d_in[8];
  const float* conv_bias = (const float*)d_in[9];
  const float* convb_w   = (const float*)d_in[10];
  const float* convb_bias= (const float*)d_in[11];
  const float* xproj_w   = (const float*)d_in[12];
  const float* xprojb_w  = (const float*)d_in[13];
  const float* dt_w      = (const float*)d_in[14];
  const float* dt_bias   = (const float*)d_in[15];
  const float* dtb_w     = (const float*)d_in[16];
  const float* dtb_bias  = (const float*)d_in[17];
  const float* A_log     = (const float*)d_in[18];
  const float* A_b_log   = (const float*)d_in[19];
  const float* Dp        = (const float*)d_in[20];
  const float* Dp_b      = (const float*)d_in[21];
  const float* norm_w    = (const float*)d_in[22];
  const float* out_w     = (const float*)d_in[23];
  const float* post_w    = (const float*)d_in[24];
  const float* post_b    = (const float*)d_in[25];
  float* ws  = (float*)d_ws;
  float* out = (float*)d_out;

  k_pool<<<NPOOLB+1, 256, 0, stream>>>(img1, img2, pre_w, pre_b, ln_g, ln_b,
                                       in_w, in_b_w, A_log, A_b_log,
                                       norm_w, out_w, post_w, ws);
  k_projA<<<1024, 512, 0, stream>>>(conv_w, conv_bias, convb_w, convb_bias,
                                    xproj_w, xprojb_w, dt_w, dt_bias, dtb_w, dtb_bias, ws);
  k_scanB<<<256, 64, 0, stream>>>(ws);
  k_projC<<<512, 512, 0, stream>>>(conv_w, conv_bias, convb_w, convb_bias,
                                   xproj_w, xprojb_w, dt_w, dt_bias, dtb_w, dtb_bias,
                                   Dp, Dp_b, post_b, ws, out);
}